// Round 1
// baseline (432.232 us; speedup 1.0000x reference)
//
#include <hip/hip_runtime.h>

#define DEV __device__ __forceinline__

typedef __attribute__((ext_vector_type(4))) float f32x4;
typedef __attribute__((ext_vector_type(8))) short short8;
typedef __attribute__((ext_vector_type(4))) short s16x4;
typedef __attribute__((ext_vector_type(4))) float f32x4v;

DEV short f2bf(float f) {
  union { float f; unsigned u; } v; v.f = f;
  unsigned r = (v.u + 0x7FFFu + ((v.u >> 16) & 1u)) >> 16;
  return (short)r;
}

DEV void gload16(const void* g, void* l) {
  __builtin_amdgcn_global_load_lds(
      (const __attribute__((address_space(1))) void*)g,
      (__attribute__((address_space(3))) void*)l, 16, 0, 0);
}

// ---------------- prep kernels ----------------

__global__ __launch_bounds__(256) void k_prep_keys(const float* __restrict__ k,
                                                   short* __restrict__ o) {
  int i = (blockIdx.x * 256 + threadIdx.x) * 4;
  f32x4v v = *(const f32x4v*)(k + i);
  s16x4 s;
  s[0] = f2bf(v[0]); s[1] = f2bf(v[1]); s[2] = f2bf(v[2]); s[3] = f2bf(v[3]);
  *(s16x4*)(o + i) = s;
}

// W2 [k][n] f32 -> W2t [n][k] bf16
__global__ __launch_bounds__(256) void k_prep_w2t(const float* __restrict__ w2,
                                                  short* __restrict__ w2t) {
  __shared__ float tile[64][65];
  const int k0 = blockIdx.x * 64, n0 = blockIdx.y * 64;
  const int a = threadIdx.x & 63, q = threadIdx.x >> 6;
#pragma unroll
  for (int i = 0; i < 16; ++i) {
    int kk = i * 4 + q;
    tile[kk][a] = w2[(size_t)(k0 + kk) * 1024 + n0 + a];
  }
  __syncthreads();
#pragma unroll
  for (int i = 0; i < 16; ++i) {
    int nn = i * 4 + q;
    w2t[(size_t)(n0 + nn) * 1024 + k0 + a] = f2bf(tile[a][nn]);
  }
}

// Wkt[b][d][m] = bf16( W1[256+m][d] - W1[512+m][d] + q[b][m]*W1[768+m][d] )
__global__ __launch_bounds__(256) void k_prep_wkt(const float* __restrict__ w1,
                                                  const float* __restrict__ query,
                                                  short* __restrict__ wkt) {
  __shared__ short tile[64][257];
  const int b = blockIdx.x, d0 = blockIdx.y * 64;
  const int d = threadIdx.x & 63, mq = threadIdx.x >> 6;
#pragma unroll 4
  for (int i = 0; i < 64; ++i) {
    int m = i * 4 + mq;
    float wb = w1[(size_t)(256 + m) * 1024 + d0 + d];
    float wc = w1[(size_t)(512 + m) * 1024 + d0 + d];
    float wd = w1[(size_t)(768 + m) * 1024 + d0 + d];
    float qv = query[b * 256 + m];
    tile[d][m] = f2bf(wb - wc + qv * wd);
  }
  __syncthreads();
  const int m = threadIdx.x;
  for (int dd = 0; dd < 64; ++dd)
    wkt[((size_t)b * 1024 + d0 + dd) * 256 + m] = tile[dd][m];
}

// biasb[b][d] = b1[d] + sum_m q[b][m]*(W1[m][d] + W1[512+m][d])
__global__ __launch_bounds__(256) void k_prep_bias(const float* __restrict__ w1,
                                                   const float* __restrict__ query,
                                                   const float* __restrict__ b1,
                                                   float* __restrict__ biasb) {
  const int b = blockIdx.x, t = threadIdx.x;
  float a0 = 0, a1 = 0, a2 = 0, a3 = 0;
  for (int m = 0; m < 256; ++m) {
    float qv = query[b * 256 + m];
    const float* ra = w1 + (size_t)m * 1024;
    const float* rc = w1 + (size_t)(512 + m) * 1024;
    a0 += qv * (ra[t] + rc[t]);
    a1 += qv * (ra[t + 256] + rc[t + 256]);
    a2 += qv * (ra[t + 512] + rc[t + 512]);
    a3 += qv * (ra[t + 768] + rc[t + 768]);
  }
  float* o = biasb + b * 1024;
  o[t] = a0 + b1[t];
  o[t + 256] = a1 + b1[t + 256];
  o[t + 512] = a2 + b1[t + 512];
  o[t + 768] = a3 + b1[t + 768];
}

// ---------------- GEMM (TN: C[i][j] = sum_k A[i][k]*B[j][k]) ----------------
// MODE 1: per-batch keys@Wk + bias, relu -> h1 (bf16)
// MODE 2: h1@W2t + b2, relu, dot w_score -> score partials (per coltile, per wc-wave)

template <int MODE>
__global__ __launch_bounds__(256) void k_gemm(const short* __restrict__ A,
                                              const short* __restrict__ B,
                                              const float* __restrict__ bias,
                                              const float* __restrict__ wscore,
                                              short* __restrict__ hout,
                                              float* __restrict__ spart) {
  __shared__ short lds[8192];  // A tile [128][32] @0, B tile [128][32] @4096 (XOR-swizzled slots)
  const int tid = threadIdx.x;
  const int bx = blockIdx.x;

  int strideA, strideB, KT;
  const short *Ab, *Bb;
  const float *biasp = nullptr, *wsp = nullptr;
  short* houtp = nullptr;
  float* spp = nullptr;

  if constexpr (MODE == 1) {
    const int b = bx >> 6, rt = (bx >> 3) & 7, ct = bx & 7;
    strideA = 256; strideB = 256; KT = 8;
    Ab = A + ((size_t)b * 1024 + rt * 128) * 256;
    Bb = B + ((size_t)b * 1024 + ct * 128) * 256;
    biasp = bias + b * 1024 + ct * 128;
    houtp = hout + ((size_t)b * 1024 + rt * 128) * 1024 + ct * 128;
  } else {
    const int rt = bx >> 3, ct = bx & 7;
    strideA = 1024; strideB = 1024; KT = 32;
    Ab = A + (size_t)rt * 128 * 1024;
    Bb = B + (size_t)ct * 128 * 1024;
    biasp = bias + ct * 128;
    wsp = wscore + ct * 128;
    spp = spart;  // offset computed in epilogue (per wc)
  }

  // staging invariants: slot s -> (row=s>>2, sp=s&3), source kgroup = sp ^ ((row>>1)&3)
  const short* ga[4];
  int lof[4];
#pragma unroll
  for (int j = 0; j < 2; ++j) {
    int s = j * 256 + tid;
    int row = s >> 2;
    int kg = (s & 3) ^ ((row >> 1) & 3);
    ga[j] = Ab + (size_t)row * strideA + kg * 8;
    lof[j] = s * 8;
    ga[j + 2] = Bb + (size_t)row * strideB + kg * 8;
    lof[j + 2] = 4096 + s * 8;
  }

  const int lane = tid & 63, l15 = lane & 15, l4 = lane >> 4;
  const int wid = tid >> 6, wr = wid >> 1, wc = wid & 1;
  const int rowA = wr * 64 + l15;
  const int offA = rowA * 32 + ((l4 ^ ((rowA >> 1) & 3)) * 8);
  const int rowB = wc * 64 + l15;
  const int offB = 4096 + rowB * 32 + ((l4 ^ ((rowB >> 1) & 3)) * 8);

  f32x4 zero = {0.f, 0.f, 0.f, 0.f};
  f32x4 acc[4][4];
#pragma unroll
  for (int m = 0; m < 4; ++m)
#pragma unroll
    for (int n = 0; n < 4; ++n) acc[m][n] = zero;

#pragma unroll
  for (int j = 0; j < 4; ++j) gload16(ga[j], &lds[lof[j]]);

  for (int kt = 0; kt < KT; ++kt) {
    __syncthreads();  // tile kt ready (drains vmcnt)
    short8 af[4], bf[4];
#pragma unroll
    for (int m = 0; m < 4; ++m) af[m] = *(const short8*)&lds[offA + m * 512];
#pragma unroll
    for (int n = 0; n < 4; ++n) bf[n] = *(const short8*)&lds[offB + n * 512];
    __syncthreads();  // all waves done reading
    if (kt + 1 < KT) {
#pragma unroll
      for (int j = 0; j < 4; ++j) gload16(ga[j] + (kt + 1) * 32, &lds[lof[j]]);
    }
#pragma unroll
    for (int m = 0; m < 4; ++m)
#pragma unroll
      for (int n = 0; n < 4; ++n)
        acc[m][n] = __builtin_amdgcn_mfma_f32_16x16x32_bf16(af[m], bf[n], acc[m][n], 0, 0, 0);
  }

  if constexpr (MODE == 1) {
    float bv[4];
#pragma unroll
    for (int n = 0; n < 4; ++n) bv[n] = biasp[wc * 64 + n * 16 + l15];
#pragma unroll
    for (int m = 0; m < 4; ++m) {
#pragma unroll
      for (int r = 0; r < 4; ++r) {
        int row = wr * 64 + m * 16 + l4 * 4 + r;
#pragma unroll
        for (int n = 0; n < 4; ++n) {
          int col = wc * 64 + n * 16 + l15;
          float v = acc[m][n][r] + bv[n];
          houtp[(size_t)row * 1024 + col] = f2bf(fmaxf(v, 0.f));
        }
      }
    }
  } else {
    const int rt = bx >> 3, ct = bx & 7;
    float bv[4], wv[4];
#pragma unroll
    for (int n = 0; n < 4; ++n) {
      int c = wc * 64 + n * 16 + l15;
      bv[n] = biasp[c];
      wv[n] = wsp[c];
    }
    float* so = spp + (size_t)(ct * 2 + wc) * 65536 + rt * 128;
#pragma unroll
    for (int m = 0; m < 4; ++m) {
#pragma unroll
      for (int r = 0; r < 4; ++r) {
        float s = 0.f;
#pragma unroll
        for (int n = 0; n < 4; ++n) s += fmaxf(acc[m][n][r] + bv[n], 0.f) * wv[n];
#pragma unroll
        for (int o = 1; o < 16; o <<= 1) s += __shfl_xor(s, o);
        if (l15 == 0) {
          int row = wr * 64 + m * 16 + l4 * 4 + r;
          so[row] = s;
        }
      }
    }
  }
}

// ---------------- softmax + output ----------------

__global__ __launch_bounds__(256) void k_softmax(const float* __restrict__ spart,
                                                 const float* __restrict__ mask,
                                                 const float* __restrict__ bscore,
                                                 float* __restrict__ attn) {
  const int b = blockIdx.x, tid = threadIdx.x;
  __shared__ float sm[1024];
  __shared__ float red[8];
  const float bs = bscore[0];
  float lmax = -3.0e38f;
  for (int t = tid; t < 1024; t += 256) {
    float s = bs;
#pragma unroll
    for (int c = 0; c < 16; ++c) s += spart[(size_t)c * 65536 + b * 1024 + t];
    float lg = s + mask[b * 1024 + t] * (-1e9f);
    sm[t] = lg;
    lmax = fmaxf(lmax, lg);
  }
  for (int o = 32; o; o >>= 1) lmax = fmaxf(lmax, __shfl_xor(lmax, o));
  const int wid = tid >> 6, lane = tid & 63;
  if (lane == 0) red[wid] = lmax;
  __syncthreads();
  float bmax = fmaxf(fmaxf(red[0], red[1]), fmaxf(red[2], red[3]));
  float lsum = 0.f;
  for (int t = tid; t < 1024; t += 256) {
    float e = __expf(sm[t] - bmax);
    sm[t] = e;
    lsum += e;
  }
  for (int o = 32; o; o >>= 1) lsum += __shfl_xor(lsum, o);
  __syncthreads();
  if (lane == 0) red[wid] = lsum;
  __syncthreads();
  float inv = 1.0f / (red[0] + red[1] + red[2] + red[3]);
  for (int t = tid; t < 1024; t += 256) attn[b * 1024 + t] = sm[t] * inv;
}

__global__ __launch_bounds__(256) void k_out(const float* __restrict__ attn,
                                             const float* __restrict__ values,
                                             float* __restrict__ out) {
  const int b = blockIdx.x >> 2;
  const int d = (blockIdx.x & 3) * 256 + threadIdx.x;
  __shared__ float at[1024];
  for (int t = threadIdx.x; t < 1024; t += 256) at[t] = attn[b * 1024 + t];
  __syncthreads();
  const float* vb = values + (size_t)b * 1024 * 1024 + d;
  float acc = 0.f;
#pragma unroll 8
  for (int t = 0; t < 1024; ++t) acc += at[t] * vb[(size_t)t * 1024];
  out[b * 1024 + d] = acc;
}

// ---------------- launch ----------------

extern "C" void kernel_launch(void* const* d_in, const int* in_sizes, int n_in,
                              void* d_out, int out_size, void* d_ws, size_t ws_size,
                              hipStream_t stream) {
  const float* query  = (const float*)d_in[0];
  const float* keys   = (const float*)d_in[1];
  const float* values = (const float*)d_in[2];
  const float* mask   = (const float*)d_in[3];
  const float* W1     = (const float*)d_in[4];
  const float* b1     = (const float*)d_in[5];
  const float* W2     = (const float*)d_in[6];
  const float* b2     = (const float*)d_in[7];
  const float* wscore = (const float*)d_in[8];
  const float* bscore = (const float*)d_in[9];
  float* out = (float*)d_out;

  char* ws = (char*)d_ws;
  short* keysb = (short*)(ws);                   // 33,554,432 B
  short* wkt   = (short*)(ws + 33554432ull);     // 33,554,432 B
  short* w2t   = (short*)(ws + 67108864ull);     //  2,097,152 B
  float* biasb = (float*)(ws + 69206016ull);     //    262,144 B
  short* h1    = (short*)(ws + 69468160ull);     // 134,217,728 B
  float* spart = (float*)(ws + 203685888ull);    //  4,194,304 B
  float* attn  = (float*)(ws + 207880192ull);    //    262,144 B  (total ~208 MB)

  k_prep_keys<<<16384, 256, 0, stream>>>(keys, keysb);
  k_prep_w2t<<<dim3(16, 16), 256, 0, stream>>>(W2, w2t);
  k_prep_wkt<<<dim3(64, 16), 256, 0, stream>>>(W1, query, wkt);
  k_prep_bias<<<64, 256, 0, stream>>>(W1, query, b1, biasb);

  k_gemm<1><<<4096, 256, 0, stream>>>(keysb, wkt, biasb, nullptr, h1, nullptr);
  k_gemm<2><<<4096, 256, 0, stream>>>(h1, w2t, b2, wscore, nullptr, spart);

  k_softmax<<<64, 256, 0, stream>>>(spart, mask, bscore, attn);
  k_out<<<256, 256, 0, stream>>>(attn, values, out);
}

// Round 2
// 331.753 us; speedup vs baseline: 1.3029x; 1.3029x over previous
//
#include <hip/hip_runtime.h>

#define DEV __device__ __forceinline__

typedef __attribute__((ext_vector_type(4))) float f32x4;
typedef __attribute__((ext_vector_type(8))) short short8;
typedef __attribute__((ext_vector_type(4))) short s16x4;
typedef __attribute__((ext_vector_type(4))) float f32x4v;

DEV short f2bf(float f) {
  union { float f; unsigned u; } v; v.f = f;
  unsigned r = (v.u + 0x7FFFu + ((v.u >> 16) & 1u)) >> 16;
  return (short)r;
}

DEV void gload16(const void* g, void* l) {
  __builtin_amdgcn_global_load_lds(
      (const __attribute__((address_space(1))) void*)g,
      (__attribute__((address_space(3))) void*)l, 16, 0, 0);
}

#define BAR() __builtin_amdgcn_s_barrier()
#define LGKM0()                                          \
  {                                                      \
    asm volatile("s_waitcnt lgkmcnt(0)" ::: "memory");   \
    __builtin_amdgcn_sched_barrier(0);                   \
  }
#define VMW(n)                                                \
  {                                                           \
    asm volatile("s_waitcnt vmcnt(" #n ")" ::: "memory");     \
    __builtin_amdgcn_sched_barrier(0);                        \
  }

#define RD_A(pb, qrt)                                                          \
  _Pragma("unroll") for (int m_ = 0; m_ < 4; ++m_) {                           \
    af[m_][0] = *(const short8*)&lds[(pb) + aoff0 + ((qrt) * 4 + m_) * 1024];  \
    af[m_][1] = *(const short8*)&lds[(pb) + aoff1 + ((qrt) * 4 + m_) * 1024];  \
  }
#define RD_B(pb, nh)                                                             \
  _Pragma("unroll") for (int n_ = 0; n_ < 2; ++n_) {                             \
    bf[nh][n_][0] = *(const short8*)&lds[(pb) + boff0 + ((nh) * 2 + n_) * 1024]; \
    bf[nh][n_][1] = *(const short8*)&lds[(pb) + boff1 + ((nh) * 2 + n_) * 1024]; \
  }
#define MFMA_Q(mq, nh)                                                           \
  __builtin_amdgcn_s_setprio(1);                                                 \
  _Pragma("unroll") for (int m_ = 0; m_ < 4; ++m_) {                             \
    _Pragma("unroll") for (int n_ = 0; n_ < 2; ++n_) {                           \
      acc[(mq) * 4 + m_][(nh) * 2 + n_] =                                        \
          __builtin_amdgcn_mfma_f32_16x16x32_bf16(                               \
              af[m_][0], bf[nh][n_][0], acc[(mq) * 4 + m_][(nh) * 2 + n_], 0, 0, \
              0);                                                                \
      acc[(mq) * 4 + m_][(nh) * 2 + n_] =                                        \
          __builtin_amdgcn_mfma_f32_16x16x32_bf16(                               \
              af[m_][1], bf[nh][n_][1], acc[(mq) * 4 + m_][(nh) * 2 + n_], 0, 0, \
              0);                                                                \
    }                                                                            \
  }                                                                              \
  __builtin_amdgcn_s_setprio(0);

struct FullTag { static constexpr bool value = true; };
struct LastTag { static constexpr bool value = false; };

// ---------------- prep kernels ----------------

__global__ __launch_bounds__(256) void k_prep_keys(const float* __restrict__ k,
                                                   short* __restrict__ o) {
  int i = (blockIdx.x * 256 + threadIdx.x) * 4;
  f32x4v v = *(const f32x4v*)(k + i);
  s16x4 s;
  s[0] = f2bf(v[0]); s[1] = f2bf(v[1]); s[2] = f2bf(v[2]); s[3] = f2bf(v[3]);
  *(s16x4*)(o + i) = s;
}

// W2 [k][n] f32 -> W2t [n][k] bf16
__global__ __launch_bounds__(256) void k_prep_w2t(const float* __restrict__ w2,
                                                  short* __restrict__ w2t) {
  __shared__ float tile[64][65];
  const int k0 = blockIdx.x * 64, n0 = blockIdx.y * 64;
  const int a = threadIdx.x & 63, q = threadIdx.x >> 6;
#pragma unroll
  for (int i = 0; i < 16; ++i) {
    int kk = i * 4 + q;
    tile[kk][a] = w2[(size_t)(k0 + kk) * 1024 + n0 + a];
  }
  __syncthreads();
#pragma unroll
  for (int i = 0; i < 16; ++i) {
    int nn = i * 4 + q;
    w2t[(size_t)(n0 + nn) * 1024 + k0 + a] = f2bf(tile[a][nn]);
  }
}

// Wkt[b][d][m] = bf16( W1[256+m][d] - W1[512+m][d] + q[b][m]*W1[768+m][d] )
__global__ __launch_bounds__(256) void k_prep_wkt(const float* __restrict__ w1,
                                                  const float* __restrict__ query,
                                                  short* __restrict__ wkt) {
  __shared__ short tile[64][257];
  const int b = blockIdx.x, d0 = blockIdx.y * 64;
  const int d = threadIdx.x & 63, mq = threadIdx.x >> 6;
#pragma unroll 4
  for (int i = 0; i < 64; ++i) {
    int m = i * 4 + mq;
    float wb = w1[(size_t)(256 + m) * 1024 + d0 + d];
    float wc = w1[(size_t)(512 + m) * 1024 + d0 + d];
    float wd = w1[(size_t)(768 + m) * 1024 + d0 + d];
    float qv = query[b * 256 + m];
    tile[d][m] = f2bf(wb - wc + qv * wd);
  }
  __syncthreads();
  const int m = threadIdx.x;
  for (int dd = 0; dd < 64; ++dd)
    wkt[((size_t)b * 1024 + d0 + dd) * 256 + m] = tile[dd][m];
}

// biasb[b][d] = b1[d] + sum_m q[b][m]*(W1[m][d] + W1[512+m][d])
__global__ __launch_bounds__(256) void k_prep_bias(const float* __restrict__ w1,
                                                   const float* __restrict__ query,
                                                   const float* __restrict__ b1,
                                                   float* __restrict__ biasb) {
  const int b = blockIdx.x >> 2, t = (blockIdx.x & 3) * 256 + threadIdx.x;
  float a0 = 0.f;
  for (int m = 0; m < 256; ++m) {
    float qv = query[b * 256 + m];
    a0 += qv * (w1[(size_t)m * 1024 + t] + w1[(size_t)(512 + m) * 1024 + t]);
  }
  biasb[b * 1024 + t] = a0 + b1[t];
}

// ---------------- 8-phase 256x256 GEMM (TN: C[i][j] = sum_k A[i][k]*B[j][k]) ----
// MODE 1: per-batch keys@Wk + bias, relu -> h1 (bf16).  M=N=1024/batch, K=256.
// MODE 2: h1@W2t + b2, relu, dot w_score -> score partials. M=65536, N=1024, K=1024.
// 512 thr (8 waves 2Mx4N), BM=BN=256, BK=64, LDS 128 KiB double-buffered,
// st-swizzle slot^=(row&7) on 16B chunks, counted vmcnt(4) at phi3/phi7 only.

template <int MODE>
__global__ __launch_bounds__(512) void k_gemm8(const short* __restrict__ A,
                                               const short* __restrict__ B,
                                               const float* __restrict__ bias,
                                               const float* __restrict__ wscore,
                                               short* __restrict__ hout,
                                               float* __restrict__ spart) {
  __shared__ short lds[65536];  // 128 KiB: buf{0,1} x {A h0,A h1,B h0,B h1} x 16KB
  constexpr int SK = (MODE == 1) ? 256 : 1024;
  constexpr int KT = (MODE == 1) ? 4 : 16;

  const int tid = threadIdx.x;
  const int bx = blockIdx.x;
  const int L = (bx & 7) * 128 + (bx >> 3);  // XCD-bijective swizzle (1024%8==0)

  const short *Ab, *Bb;
  const float *biasp, *wsp = nullptr;
  short* houtp = nullptr;
  int rt, ct;
  if constexpr (MODE == 1) {
    const int b = L >> 4;
    rt = (L >> 2) & 3; ct = L & 3;
    Ab = A + ((size_t)b * 1024 + rt * 256) * 256;
    Bb = B + ((size_t)b * 1024 + ct * 256) * 256;
    biasp = bias + b * 1024 + ct * 256;
    houtp = hout + ((size_t)(b * 1024 + rt * 256)) * 1024 + ct * 256;
  } else {
    rt = L >> 2; ct = L & 3;
    Ab = A + (size_t)rt * 256 * 1024;
    Bb = B + (size_t)ct * 256 * 1024;
    biasp = bias + ct * 256;
    wsp = wscore + ct * 256;
  }

  // staging constants: chunk c -> row=c>>3, stored slot=c&7, src k16 = slot^(row&7)
  const int c0 = tid, c1 = 512 + tid;
  const int r0 = c0 >> 3, k0 = ((c0 & 7) ^ (r0 & 7)) * 8;
  const int r1 = c1 >> 3, k1 = ((c1 & 7) ^ (r1 & 7)) * 8;

  auto STAGE = [&](const short* gb, int kt, int half, int ldsb) {
    gload16(gb + (size_t)(half * 128 + r0) * SK + kt * 64 + k0, &lds[ldsb + c0 * 8]);
    gload16(gb + (size_t)(half * 128 + r1) * SK + kt * 64 + k1, &lds[ldsb + c1 * 8]);
  };

  // fragment-read constants
  const int lane = tid & 63, l15 = lane & 15, l4 = lane >> 4;
  const int wid = tid >> 6, wr = wid >> 2, wc = wid & 3;
  const int aoff0 = wr * 8192 + l15 * 64 + ((l4 ^ (l15 & 7)) * 8);
  const int aoff1 = wr * 8192 + l15 * 64 + (((4 + l4) ^ (l15 & 7)) * 8);
  const int boff0 = 16384 + (wc >> 1) * 8192 + (wc & 1) * 4096 + l15 * 64 +
                    ((l4 ^ (l15 & 7)) * 8);
  const int boff1 = 16384 + (wc >> 1) * 8192 + (wc & 1) * 4096 + l15 * 64 +
                    (((4 + l4) ^ (l15 & 7)) * 8);

  f32x4 acc[8][4];
#pragma unroll
  for (int m = 0; m < 8; ++m)
#pragma unroll
    for (int n = 0; n < 4; ++n) acc[m][n] = f32x4{0.f, 0.f, 0.f, 0.f};
  short8 af[4][2];
  short8 bf[2][2][2];

  // prologue: tile0 full + A(tile1); drain tile0, keep A(1) in flight
  STAGE(Ab, 0, 0, 0);
  STAGE(Ab, 0, 1, 8192);
  STAGE(Bb, 0, 0, 16384);
  STAGE(Bb, 0, 1, 24576);
  STAGE(Ab, 1, 0, 32768);
  STAGE(Ab, 1, 1, 40960);
  VMW(4);
  BAR();

  auto body = [&](int t, auto tag) {
    constexpr bool FULL = decltype(tag)::value;
    const int p = (t & 1) << 15;
    const int q = p ^ 32768;
    // phi0: tile t quadrant Q00
    RD_A(p, 0); RD_B(p, 0);
    STAGE(Bb, t + 1, 0, q + 16384);
    BAR(); LGKM0(); MFMA_Q(0, 0); BAR();
    // phi1: Q01 (af=a0, bf1)
    RD_B(p, 1);
    STAGE(Bb, t + 1, 1, q + 24576);
    BAR(); LGKM0(); MFMA_Q(0, 1); BAR();
    // phi2: Q11 (af<-a1)
    RD_A(p, 1);
    if constexpr (FULL) STAGE(Bb, t + 2, 0, p + 16384);
    BAR(); LGKM0(); MFMA_Q(1, 1); BAR();
    // phi3: Q10
    if constexpr (FULL) STAGE(Bb, t + 2, 1, p + 24576);
    BAR();
    MFMA_Q(1, 0);
    if constexpr (FULL) { VMW(4); } else { VMW(0); }
    BAR();
    // phi4: tile t+1 (buf q) Q00
    RD_A(q, 0); RD_B(q, 0);
    if constexpr (FULL) STAGE(Ab, t + 2, 0, p + 0);
    BAR(); LGKM0(); MFMA_Q(0, 0); BAR();
    // phi5: Q01
    RD_B(q, 1);
    if constexpr (FULL) STAGE(Ab, t + 2, 1, p + 8192);
    BAR(); LGKM0(); MFMA_Q(0, 1); BAR();
    // phi6: Q11
    RD_A(q, 1);
    BAR(); LGKM0(); MFMA_Q(1, 1); BAR();
    // phi7: Q10 + prefetch A(t+3) both halves
    if constexpr (FULL) { STAGE(Ab, t + 3, 0, q + 0); STAGE(Ab, t + 3, 1, q + 8192); }
    BAR();
    MFMA_Q(1, 0);
    if constexpr (FULL) { VMW(4); }
    BAR();
  };

#pragma nounroll
  for (int i = 0; i < KT / 2 - 1; ++i) body(2 * i, FullTag{});
  body(KT - 2, LastTag{});

  // ---------------- epilogue ----------------
  if constexpr (MODE == 1) {
    float bv[4];
#pragma unroll
    for (int n = 0; n < 4; ++n) bv[n] = biasp[wc * 64 + n * 16 + l15];
#pragma unroll
    for (int m = 0; m < 8; ++m) {
#pragma unroll
      for (int r2 = 0; r2 < 4; ++r2) {
        int row = wr * 128 + m * 16 + l4 * 4 + r2;
#pragma unroll
        for (int n = 0; n < 4; ++n) {
          int col = wc * 64 + n * 16 + l15;
          houtp[(size_t)row * 1024 + col] = f2bf(fmaxf(acc[m][n][r2] + bv[n], 0.f));
        }
      }
    }
  } else {
    float bv[4], wv[4];
#pragma unroll
    for (int n = 0; n < 4; ++n) {
      int c = wc * 64 + n * 16 + l15;
      bv[n] = biasp[c];
      wv[n] = wsp[c];
    }
    float* so = spart + ((size_t)(ct * 4 + wc) << 16) + rt * 256 + wr * 128;
#pragma unroll
    for (int m = 0; m < 8; ++m) {
#pragma unroll
      for (int r2 = 0; r2 < 4; ++r2) {
        float s = 0.f;
#pragma unroll
        for (int n = 0; n < 4; ++n) s += fmaxf(acc[m][n][r2] + bv[n], 0.f) * wv[n];
        s += __shfl_xor(s, 1);
        s += __shfl_xor(s, 2);
        s += __shfl_xor(s, 4);
        s += __shfl_xor(s, 8);
        if (l15 == 0) so[m * 16 + l4 * 4 + r2] = s;
      }
    }
  }
}

// ---------------- softmax + output ----------------

__global__ __launch_bounds__(256) void k_softmax(const float* __restrict__ spart,
                                                 const float* __restrict__ mask,
                                                 const float* __restrict__ bscore,
                                                 float* __restrict__ attn) {
  const int b = blockIdx.x, tid = threadIdx.x;
  __shared__ float sm[1024];
  __shared__ float red[8];
  const float bs = bscore[0];
  float lmax = -3.0e38f;
  for (int t = tid; t < 1024; t += 256) {
    float s = bs;
#pragma unroll
    for (int c = 0; c < 16; ++c) s += spart[(size_t)c * 65536 + b * 1024 + t];
    float lg = s + mask[b * 1024 + t] * (-1e9f);
    sm[t] = lg;
    lmax = fmaxf(lmax, lg);
  }
  for (int o = 32; o; o >>= 1) lmax = fmaxf(lmax, __shfl_xor(lmax, o));
  const int wid = tid >> 6, lane = tid & 63;
  if (lane == 0) red[wid] = lmax;
  __syncthreads();
  float bmax = fmaxf(fmaxf(red[0], red[1]), fmaxf(red[2], red[3]));
  float lsum = 0.f;
  for (int t = tid; t < 1024; t += 256) {
    float e = __expf(sm[t] - bmax);
    sm[t] = e;
    lsum += e;
  }
  for (int o = 32; o; o >>= 1) lsum += __shfl_xor(lsum, o);
  __syncthreads();
  if (lane == 0) red[wid] = lsum;
  __syncthreads();
  float inv = 1.0f / (red[0] + red[1] + red[2] + red[3]);
  for (int t = tid; t < 1024; t += 256) attn[b * 1024 + t] = sm[t] * inv;
}

__global__ __launch_bounds__(256) void k_out(const float* __restrict__ attn,
                                             const float* __restrict__ values,
                                             float* __restrict__ out) {
  const int b = blockIdx.x >> 2;
  const int d = (blockIdx.x & 3) * 256 + threadIdx.x;
  __shared__ float at[1024];
  for (int t = threadIdx.x; t < 1024; t += 256) at[t] = attn[b * 1024 + t];
  __syncthreads();
  const float* vb = values + (size_t)b * 1024 * 1024 + d;
  float acc = 0.f;
#pragma unroll 8
  for (int t = 0; t < 1024; ++t) acc += at[t] * vb[(size_t)t * 1024];
  out[b * 1024 + d] = acc;
}

// ---------------- launch ----------------

extern "C" void kernel_launch(void* const* d_in, const int* in_sizes, int n_in,
                              void* d_out, int out_size, void* d_ws, size_t ws_size,
                              hipStream_t stream) {
  const float* query  = (const float*)d_in[0];
  const float* keys   = (const float*)d_in[1];
  const float* values = (const float*)d_in[2];
  const float* mask   = (const float*)d_in[3];
  const float* W1     = (const float*)d_in[4];
  const float* b1     = (const float*)d_in[5];
  const float* W2     = (const float*)d_in[6];
  const float* b2     = (const float*)d_in[7];
  const float* wscore = (const float*)d_in[8];
  const float* bscore = (const float*)d_in[9];
  float* out = (float*)d_out;

  char* ws = (char*)d_ws;
  short* keysb = (short*)(ws);                   // 33,554,432 B
  short* wkt   = (short*)(ws + 33554432ull);     // 33,554,432 B
  short* w2t   = (short*)(ws + 67108864ull);     //  2,097,152 B
  float* biasb = (float*)(ws + 69206016ull);     //    262,144 B
  short* h1    = (short*)(ws + 69468160ull);     // 134,217,728 B
  float* spart = (float*)(ws + 203685888ull);    //  4,194,304 B
  float* attn  = (float*)(ws + 207880192ull);    //    262,144 B  (total ~208 MB)

  k_prep_keys<<<16384, 256, 0, stream>>>(keys, keysb);
  k_prep_w2t<<<dim3(16, 16), 256, 0, stream>>>(W2, w2t);
  k_prep_wkt<<<dim3(64, 16), 256, 0, stream>>>(W1, query, wkt);
  k_prep_bias<<<256, 256, 0, stream>>>(W1, query, b1, biasb);

  k_gemm8<1><<<1024, 512, 0, stream>>>(keysb, wkt, biasb, nullptr, h1, nullptr);
  k_gemm8<2><<<1024, 512, 0, stream>>>(h1, w2t, b2, wscore, nullptr, spart);

  k_softmax<<<64, 256, 0, stream>>>(spart, mask, bscore, attn);
  k_out<<<256, 256, 0, stream>>>(attn, values, out);
}

// Round 3
// 284.374 us; speedup vs baseline: 1.5199x; 1.1666x over previous
//
#include <hip/hip_runtime.h>

#define DEV __device__ __forceinline__

typedef __attribute__((ext_vector_type(4))) float f32x4;
typedef __attribute__((ext_vector_type(8))) short short8;
typedef __attribute__((ext_vector_type(4))) short s16x4;
typedef __attribute__((ext_vector_type(4))) float f32x4v;

DEV short f2bf(float f) {
  union { float f; unsigned u; } v; v.f = f;
  unsigned r = (v.u + 0x7FFFu + ((v.u >> 16) & 1u)) >> 16;
  return (short)r;
}

DEV void gload16(const void* g, void* l) {
  __builtin_amdgcn_global_load_lds(
      (const __attribute__((address_space(1))) void*)g,
      (__attribute__((address_space(3))) void*)l, 16, 0, 0);
}

#define BAR() __builtin_amdgcn_s_barrier()
#define LGKM0()                                          \
  {                                                      \
    asm volatile("s_waitcnt lgkmcnt(0)" ::: "memory");   \
    __builtin_amdgcn_sched_barrier(0);                   \
  }
#define VMW(n)                                                \
  {                                                           \
    asm volatile("s_waitcnt vmcnt(" #n ")" ::: "memory");     \
    __builtin_amdgcn_sched_barrier(0);                        \
  }

#define RD_A(pb, qrt)                                                          \
  _Pragma("unroll") for (int m_ = 0; m_ < 4; ++m_) {                           \
    af[m_][0] = *(const short8*)&lds[(pb) + aoff0 + ((qrt) * 4 + m_) * 1024];  \
    af[m_][1] = *(const short8*)&lds[(pb) + aoff1 + ((qrt) * 4 + m_) * 1024];  \
  }
#define RD_B(pb, nh)                                                             \
  _Pragma("unroll") for (int n_ = 0; n_ < 2; ++n_) {                             \
    bf[nh][n_][0] = *(const short8*)&lds[(pb) + boff0 + ((nh) * 2 + n_) * 1024]; \
    bf[nh][n_][1] = *(const short8*)&lds[(pb) + boff1 + ((nh) * 2 + n_) * 1024]; \
  }
#define MFMA_Q(mq, nh)                                                           \
  __builtin_amdgcn_s_setprio(1);                                                 \
  _Pragma("unroll") for (int m_ = 0; m_ < 4; ++m_) {                             \
    _Pragma("unroll") for (int n_ = 0; n_ < 2; ++n_) {                           \
      acc[(mq) * 4 + m_][(nh) * 2 + n_] =                                        \
          __builtin_amdgcn_mfma_f32_16x16x32_bf16(                               \
              af[m_][0], bf[nh][n_][0], acc[(mq) * 4 + m_][(nh) * 2 + n_], 0, 0, \
              0);                                                                \
      acc[(mq) * 4 + m_][(nh) * 2 + n_] =                                        \
          __builtin_amdgcn_mfma_f32_16x16x32_bf16(                               \
              af[m_][1], bf[nh][n_][1], acc[(mq) * 4 + m_][(nh) * 2 + n_], 0, 0, \
              0);                                                                \
    }                                                                            \
  }                                                                              \
  __builtin_amdgcn_s_setprio(0);

struct FullTag { static constexpr bool value = true; };
struct LastTag { static constexpr bool value = false; };

// ---------------- prep kernels ----------------

__global__ __launch_bounds__(256) void k_prep_keys(const float* __restrict__ k,
                                                   short* __restrict__ o) {
  int i = (blockIdx.x * 256 + threadIdx.x) * 8;
  f32x4v v0 = *(const f32x4v*)(k + i);
  f32x4v v1 = *(const f32x4v*)(k + i + 4);
  short8 s;
  s[0] = f2bf(v0[0]); s[1] = f2bf(v0[1]); s[2] = f2bf(v0[2]); s[3] = f2bf(v0[3]);
  s[4] = f2bf(v1[0]); s[5] = f2bf(v1[1]); s[6] = f2bf(v1[2]); s[7] = f2bf(v1[3]);
  *(short8*)(o + i) = s;
}

// W2 [k][n] f32 -> W2t [n][k] bf16
__global__ __launch_bounds__(256) void k_prep_w2t(const float* __restrict__ w2,
                                                  short* __restrict__ w2t) {
  __shared__ float tile[64][65];
  const int k0 = blockIdx.x * 64, n0 = blockIdx.y * 64;
  const int a = threadIdx.x & 63, q = threadIdx.x >> 6;
#pragma unroll
  for (int i = 0; i < 16; ++i) {
    int kk = i * 4 + q;
    tile[kk][a] = w2[(size_t)(k0 + kk) * 1024 + n0 + a];
  }
  __syncthreads();
#pragma unroll
  for (int i = 0; i < 16; ++i) {
    int nn = i * 4 + q;
    w2t[(size_t)(n0 + nn) * 1024 + k0 + a] = f2bf(tile[a][nn]);
  }
}

// Wkt[b][d][m] = bf16( W1[256+m][d] - W1[512+m][d] + q[b][m]*W1[768+m][d] )
// + fused bias: biasb[b][d] = b1[d] + sum_m q[b][m]*(W1[m][d] + W1[512+m][d])
__global__ __launch_bounds__(256) void k_prep_wkt(const float* __restrict__ w1,
                                                  const float* __restrict__ query,
                                                  const float* __restrict__ b1,
                                                  short* __restrict__ wkt,
                                                  float* __restrict__ biasb) {
  __shared__ short tile[64][257];
  __shared__ float redm[64][4];
  const int b = blockIdx.x, d0 = blockIdx.y * 64;
  const int d = threadIdx.x & 63, mq = threadIdx.x >> 6;
  float bacc = 0.f;
#pragma unroll 4
  for (int i = 0; i < 64; ++i) {
    int m = i * 4 + mq;
    float qv = query[b * 256 + m];
    float wa = w1[(size_t)m * 1024 + d0 + d];
    float wb = w1[(size_t)(256 + m) * 1024 + d0 + d];
    float wc = w1[(size_t)(512 + m) * 1024 + d0 + d];
    float wd = w1[(size_t)(768 + m) * 1024 + d0 + d];
    tile[d][m] = f2bf(wb - wc + qv * wd);
    bacc += qv * (wa + wc);
  }
  redm[d][mq] = bacc;
  __syncthreads();
  const int m = threadIdx.x;
  for (int dd = 0; dd < 64; ++dd)
    wkt[((size_t)b * 1024 + d0 + dd) * 256 + m] = tile[dd][m];
  if (threadIdx.x < 64) {
    int dd = threadIdx.x;
    biasb[b * 1024 + d0 + dd] =
        redm[dd][0] + redm[dd][1] + redm[dd][2] + redm[dd][3] + b1[d0 + dd];
  }
}

// ---------------- 8-phase 256x256 GEMM (TN: C[i][j] = sum_k A[i][k]*B[j][k]) ----
// MODE 1: per-batch keys@Wk + bias, relu -> h1 (bf16).  M=N=1024/batch, K=256.
// MODE 2: h1@W2t + b2, relu, dot w_score -> score partials. M=65536, N=1024, K=1024.
// 512 thr (8 waves 2Mx4N), BM=BN=256, BK=64, LDS 128 KiB double-buffered,
// st-swizzle slot^=(row&7) on 16B chunks, counted vmcnt(4) at phi3/phi7 only.

template <int MODE>
__global__ __launch_bounds__(512) void k_gemm8(const short* __restrict__ A,
                                               const short* __restrict__ B,
                                               const float* __restrict__ bias,
                                               const float* __restrict__ wscore,
                                               short* __restrict__ hout,
                                               float* __restrict__ spart) {
  __shared__ short lds[65536];  // 128 KiB: buf{0,1} x {A h0,A h1,B h0,B h1} x 16KB
  constexpr int SK = (MODE == 1) ? 256 : 1024;
  constexpr int KT = (MODE == 1) ? 4 : 16;

  const int tid = threadIdx.x;
  const int bx = blockIdx.x;
  const int L = (bx & 7) * 128 + (bx >> 3);  // XCD-bijective swizzle (1024%8==0)

  const short *Ab, *Bb;
  const float *biasp, *wsp = nullptr;
  short* houtp = nullptr;
  int rt, ct;
  if constexpr (MODE == 1) {
    const int b = L >> 4;
    rt = (L >> 2) & 3; ct = L & 3;
    Ab = A + ((size_t)b * 1024 + rt * 256) * 256;
    Bb = B + ((size_t)b * 1024 + ct * 256) * 256;
    biasp = bias + b * 1024 + ct * 256;
    houtp = hout + ((size_t)(b * 1024 + rt * 256)) * 1024 + ct * 256;
  } else {
    rt = L >> 2; ct = L & 3;
    Ab = A + (size_t)rt * 256 * 1024;
    Bb = B + (size_t)ct * 256 * 1024;
    biasp = bias + ct * 256;
    wsp = wscore + ct * 256;
  }

  // staging constants: chunk c -> row=c>>3, stored slot=c&7, src k16 = slot^(row&7)
  const int c0 = tid, c1 = 512 + tid;
  const int r0 = c0 >> 3, k0 = ((c0 & 7) ^ (r0 & 7)) * 8;
  const int r1 = c1 >> 3, k1 = ((c1 & 7) ^ (r1 & 7)) * 8;

  auto STAGE = [&](const short* gb, int kt, int half, int ldsb) {
    gload16(gb + (size_t)(half * 128 + r0) * SK + kt * 64 + k0, &lds[ldsb + c0 * 8]);
    gload16(gb + (size_t)(half * 128 + r1) * SK + kt * 64 + k1, &lds[ldsb + c1 * 8]);
  };

  // fragment-read constants
  const int lane = tid & 63, l15 = lane & 15, l4 = lane >> 4;
  const int wid = tid >> 6, wr = wid >> 2, wc = wid & 3;
  const int aoff0 = wr * 8192 + l15 * 64 + ((l4 ^ (l15 & 7)) * 8);
  const int aoff1 = wr * 8192 + l15 * 64 + (((4 + l4) ^ (l15 & 7)) * 8);
  const int boff0 = 16384 + (wc >> 1) * 8192 + (wc & 1) * 4096 + l15 * 64 +
                    ((l4 ^ (l15 & 7)) * 8);
  const int boff1 = 16384 + (wc >> 1) * 8192 + (wc & 1) * 4096 + l15 * 64 +
                    (((4 + l4) ^ (l15 & 7)) * 8);

  f32x4 acc[8][4];
#pragma unroll
  for (int m = 0; m < 8; ++m)
#pragma unroll
    for (int n = 0; n < 4; ++n) acc[m][n] = f32x4{0.f, 0.f, 0.f, 0.f};
  short8 af[4][2];
  short8 bf[2][2][2];

  // prologue: tile0 full + A(tile1); drain tile0, keep A(1) in flight
  STAGE(Ab, 0, 0, 0);
  STAGE(Ab, 0, 1, 8192);
  STAGE(Bb, 0, 0, 16384);
  STAGE(Bb, 0, 1, 24576);
  STAGE(Ab, 1, 0, 32768);
  STAGE(Ab, 1, 1, 40960);
  VMW(4);
  BAR();

  auto body = [&](int t, auto tag) {
    constexpr bool FULL = decltype(tag)::value;
    const int p = (t & 1) << 15;
    const int q = p ^ 32768;
    // phi0: tile t quadrant Q00
    RD_A(p, 0); RD_B(p, 0);
    STAGE(Bb, t + 1, 0, q + 16384);
    BAR(); LGKM0(); MFMA_Q(0, 0); BAR();
    // phi1: Q01 (af=a0, bf1)
    RD_B(p, 1);
    STAGE(Bb, t + 1, 1, q + 24576);
    BAR(); LGKM0(); MFMA_Q(0, 1); BAR();
    // phi2: Q11 (af<-a1)
    RD_A(p, 1);
    if constexpr (FULL) STAGE(Bb, t + 2, 0, p + 16384);
    BAR(); LGKM0(); MFMA_Q(1, 1); BAR();
    // phi3: Q10
    if constexpr (FULL) STAGE(Bb, t + 2, 1, p + 24576);
    BAR();
    MFMA_Q(1, 0);
    if constexpr (FULL) { VMW(4); } else { VMW(0); }
    BAR();
    // phi4: tile t+1 (buf q) Q00
    RD_A(q, 0); RD_B(q, 0);
    if constexpr (FULL) STAGE(Ab, t + 2, 0, p + 0);
    BAR(); LGKM0(); MFMA_Q(0, 0); BAR();
    // phi5: Q01
    RD_B(q, 1);
    if constexpr (FULL) STAGE(Ab, t + 2, 1, p + 8192);
    BAR(); LGKM0(); MFMA_Q(0, 1); BAR();
    // phi6: Q11
    RD_A(q, 1);
    BAR(); LGKM0(); MFMA_Q(1, 1); BAR();
    // phi7: Q10 + prefetch A(t+3) both halves
    if constexpr (FULL) { STAGE(Ab, t + 3, 0, q + 0); STAGE(Ab, t + 3, 1, q + 8192); }
    BAR();
    MFMA_Q(1, 0);
    if constexpr (FULL) { VMW(4); }
    BAR();
  };

#pragma nounroll
  for (int i = 0; i < KT / 2 - 1; ++i) body(2 * i, FullTag{});
  body(KT - 2, LastTag{});

  // ---------------- epilogue ----------------
  if constexpr (MODE == 1) {
    float bv[4];
#pragma unroll
    for (int n = 0; n < 4; ++n) bv[n] = biasp[wc * 64 + n * 16 + l15];
#pragma unroll
    for (int m = 0; m < 8; ++m) {
#pragma unroll
      for (int r2 = 0; r2 < 4; ++r2) {
        int row = wr * 128 + m * 16 + l4 * 4 + r2;
#pragma unroll
        for (int n = 0; n < 4; ++n) {
          int col = wc * 64 + n * 16 + l15;
          houtp[(size_t)row * 1024 + col] = f2bf(fmaxf(acc[m][n][r2] + bv[n], 0.f));
        }
      }
    }
  } else {
    float bv[4], wv[4];
#pragma unroll
    for (int n = 0; n < 4; ++n) {
      int c = wc * 64 + n * 16 + l15;
      bv[n] = biasp[c];
      wv[n] = wsp[c];
    }
    float* so = spart + ((size_t)(ct * 4 + wc) << 16) + rt * 256 + wr * 128;
#pragma unroll
    for (int m = 0; m < 8; ++m) {
#pragma unroll
      for (int r2 = 0; r2 < 4; ++r2) {
        float s = 0.f;
#pragma unroll
        for (int n = 0; n < 4; ++n) s += fmaxf(acc[m][n][r2] + bv[n], 0.f) * wv[n];
        s += __shfl_xor(s, 1);
        s += __shfl_xor(s, 2);
        s += __shfl_xor(s, 4);
        s += __shfl_xor(s, 8);
        if (l15 == 0) so[m * 16 + l4 * 4 + r2] = s;
      }
    }
  }
}

// ---------------- softmax + output ----------------

__global__ __launch_bounds__(256) void k_softmax(const float* __restrict__ spart,
                                                 const float* __restrict__ mask,
                                                 const float* __restrict__ bscore,
                                                 float* __restrict__ attn) {
  const int b = blockIdx.x, tid = threadIdx.x;
  __shared__ float sm[1024];
  __shared__ float red[8];
  const float bs = bscore[0];
  float lmax = -3.0e38f;
  for (int t = tid; t < 1024; t += 256) {
    float s = bs;
#pragma unroll
    for (int c = 0; c < 16; ++c) s += spart[(size_t)c * 65536 + b * 1024 + t];
    float lg = s + mask[b * 1024 + t] * (-1e9f);
    sm[t] = lg;
    lmax = fmaxf(lmax, lg);
  }
  for (int o = 32; o; o >>= 1) lmax = fmaxf(lmax, __shfl_xor(lmax, o));
  const int wid = tid >> 6, lane = tid & 63;
  if (lane == 0) red[wid] = lmax;
  __syncthreads();
  float bmax = fmaxf(fmaxf(red[0], red[1]), fmaxf(red[2], red[3]));
  float lsum = 0.f;
  for (int t = tid; t < 1024; t += 256) {
    float e = __expf(sm[t] - bmax);
    sm[t] = e;
    lsum += e;
  }
  for (int o = 32; o; o >>= 1) lsum += __shfl_xor(lsum, o);
  __syncthreads();
  if (lane == 0) red[wid] = lsum;
  __syncthreads();
  float inv = 1.0f / (red[0] + red[1] + red[2] + red[3]);
  for (int t = tid; t < 1024; t += 256) attn[b * 1024 + t] = sm[t] * inv;
}

// out partials: block (b, ts): sum t in [ts*128, ts*128+128) over all 1024 d (float4/thread)
__global__ __launch_bounds__(256) void k_out(const float* __restrict__ attn,
                                             const float* __restrict__ values,
                                             float* __restrict__ part) {
  const int b = blockIdx.x >> 3, ts = blockIdx.x & 7;
  const int tid = threadIdx.x;
  __shared__ float at[128];
  if (tid < 128) at[tid] = attn[b * 1024 + ts * 128 + tid];
  __syncthreads();
  const float* vb = values + ((size_t)b * 1024 + ts * 128) * 1024 + tid * 4;
  f32x4 acc = {0.f, 0.f, 0.f, 0.f};
#pragma unroll 8
  for (int t = 0; t < 128; ++t) {
    f32x4v v = *(const f32x4v*)(vb + (size_t)t * 1024);
    float a = at[t];
    acc[0] += a * v[0]; acc[1] += a * v[1]; acc[2] += a * v[2]; acc[3] += a * v[3];
  }
  *(f32x4*)(part + ((size_t)(b * 8 + ts)) * 1024 + tid * 4) = acc;
}

__global__ __launch_bounds__(256) void k_red(const float* __restrict__ part,
                                             float* __restrict__ out) {
  const int b = blockIdx.x;
  const int c4 = threadIdx.x * 4;
  f32x4 s = {0.f, 0.f, 0.f, 0.f};
#pragma unroll
  for (int ts = 0; ts < 8; ++ts) {
    f32x4v v = *(const f32x4v*)(part + ((size_t)(b * 8 + ts)) * 1024 + c4);
    s[0] += v[0]; s[1] += v[1]; s[2] += v[2]; s[3] += v[3];
  }
  *(f32x4*)(out + b * 1024 + c4) = s;
}

// ---------------- launch ----------------

extern "C" void kernel_launch(void* const* d_in, const int* in_sizes, int n_in,
                              void* d_out, int out_size, void* d_ws, size_t ws_size,
                              hipStream_t stream) {
  const float* query  = (const float*)d_in[0];
  const float* keys   = (const float*)d_in[1];
  const float* values = (const float*)d_in[2];
  const float* mask   = (const float*)d_in[3];
  const float* W1     = (const float*)d_in[4];
  const float* b1     = (const float*)d_in[5];
  const float* W2     = (const float*)d_in[6];
  const float* b2     = (const float*)d_in[7];
  const float* wscore = (const float*)d_in[8];
  const float* bscore = (const float*)d_in[9];
  float* out = (float*)d_out;

  char* ws = (char*)d_ws;
  short* keysb = (short*)(ws);                   // 33,554,432 B
  short* wkt   = (short*)(ws + 33554432ull);     // 33,554,432 B
  short* w2t   = (short*)(ws + 67108864ull);     //  2,097,152 B
  float* biasb = (float*)(ws + 69206016ull);     //    262,144 B
  short* h1    = (short*)(ws + 69468160ull);     // 134,217,728 B
  float* spart = (float*)(ws + 203685888ull);    //  4,194,304 B
  float* attn  = (float*)(ws + 207880192ull);    //    262,144 B
  float* part  = (float*)(ws + 208142336ull);    //  2,097,152 B (total ~210 MB)

  k_prep_keys<<<8192, 256, 0, stream>>>(keys, keysb);
  k_prep_w2t<<<dim3(16, 16), 256, 0, stream>>>(W2, w2t);
  k_prep_wkt<<<dim3(64, 16), 256, 0, stream>>>(W1, query, b1, wkt, biasb);

  k_gemm8<1><<<1024, 512, 0, stream>>>(keysb, wkt, biasb, nullptr, h1, nullptr);
  k_gemm8<2><<<1024, 512, 0, stream>>>(h1, w2t, b2, wscore, nullptr, spart);

  k_softmax<<<64, 256, 0, stream>>>(spart, mask, bscore, attn);
  k_out<<<512, 256, 0, stream>>>(attn, values, part);
  k_red<<<64, 256, 0, stream>>>(part, out);
}

// Round 4
// 282.658 us; speedup vs baseline: 1.5292x; 1.0061x over previous
//
#include <hip/hip_runtime.h>

#define DEV __device__ __forceinline__

typedef __attribute__((ext_vector_type(4))) float f32x4;
typedef __attribute__((ext_vector_type(8))) short short8;
typedef __attribute__((ext_vector_type(4))) short s16x4;
typedef __attribute__((ext_vector_type(4))) float f32x4v;

DEV short f2bf(float f) {
  union { float f; unsigned u; } v; v.f = f;
  unsigned r = (v.u + 0x7FFFu + ((v.u >> 16) & 1u)) >> 16;
  return (short)r;
}

DEV void gload16(const void* g, void* l) {
  __builtin_amdgcn_global_load_lds(
      (const __attribute__((address_space(1))) void*)g,
      (__attribute__((address_space(3))) void*)l, 16, 0, 0);
}

#define BAR() __builtin_amdgcn_s_barrier()
#define LGKMW(n)                                              \
  {                                                           \
    asm volatile("s_waitcnt lgkmcnt(" #n ")" ::: "memory");   \
    __builtin_amdgcn_sched_barrier(0);                        \
  }
#define VMW(n)                                                \
  {                                                           \
    asm volatile("s_waitcnt vmcnt(" #n ")" ::: "memory");     \
    __builtin_amdgcn_sched_barrier(0);                        \
  }

#define RD_A(pb, qrt)                                                          \
  _Pragma("unroll") for (int m_ = 0; m_ < 4; ++m_) {                           \
    af[m_][0] = *(const short8*)&lds[(pb) + aoff0 + ((qrt) * 4 + m_) * 1024];  \
    af[m_][1] = *(const short8*)&lds[(pb) + aoff1 + ((qrt) * 4 + m_) * 1024];  \
  }
#define RD_B(pb, nh)                                                             \
  _Pragma("unroll") for (int n_ = 0; n_ < 2; ++n_) {                             \
    bf[nh][n_][0] = *(const short8*)&lds[(pb) + boff0 + ((nh) * 2 + n_) * 1024]; \
    bf[nh][n_][1] = *(const short8*)&lds[(pb) + boff1 + ((nh) * 2 + n_) * 1024]; \
  }
// Swapped operand order: D = mfma(bf, af) -> per-lane C-mapping:
//   C row = l15, C col = l4*4 + reg   (4 regs = 4 consecutive cols)
#define MFMA_Q(mq, nh)                                                           \
  __builtin_amdgcn_s_setprio(1);                                                 \
  _Pragma("unroll") for (int m_ = 0; m_ < 4; ++m_) {                             \
    _Pragma("unroll") for (int n_ = 0; n_ < 2; ++n_) {                           \
      acc[(mq) * 4 + m_][(nh) * 2 + n_] =                                        \
          __builtin_amdgcn_mfma_f32_16x16x32_bf16(                               \
              bf[nh][n_][0], af[m_][0], acc[(mq) * 4 + m_][(nh) * 2 + n_], 0, 0, \
              0);                                                                \
      acc[(mq) * 4 + m_][(nh) * 2 + n_] =                                        \
          __builtin_amdgcn_mfma_f32_16x16x32_bf16(                               \
              bf[nh][n_][1], af[m_][1], acc[(mq) * 4 + m_][(nh) * 2 + n_], 0, 0, \
              0);                                                                \
    }                                                                            \
  }                                                                              \
  __builtin_amdgcn_s_setprio(0);

struct FullTag { static constexpr bool value = true; };
struct LastTag { static constexpr bool value = false; };

// ---------------- prep kernels ----------------

__global__ __launch_bounds__(256) void k_prep_keys(const float* __restrict__ k,
                                                   short* __restrict__ o) {
  int i = (blockIdx.x * 256 + threadIdx.x) * 8;
  f32x4v v0 = *(const f32x4v*)(k + i);
  f32x4v v1 = *(const f32x4v*)(k + i + 4);
  short8 s;
  s[0] = f2bf(v0[0]); s[1] = f2bf(v0[1]); s[2] = f2bf(v0[2]); s[3] = f2bf(v0[3]);
  s[4] = f2bf(v1[0]); s[5] = f2bf(v1[1]); s[6] = f2bf(v1[2]); s[7] = f2bf(v1[3]);
  *(short8*)(o + i) = s;
}

// W2 [k][n] f32 -> W2t [n][k] bf16
__global__ __launch_bounds__(256) void k_prep_w2t(const float* __restrict__ w2,
                                                  short* __restrict__ w2t) {
  __shared__ float tile[64][65];
  const int k0 = blockIdx.x * 64, n0 = blockIdx.y * 64;
  const int a = threadIdx.x & 63, q = threadIdx.x >> 6;
#pragma unroll
  for (int i = 0; i < 16; ++i) {
    int kk = i * 4 + q;
    tile[kk][a] = w2[(size_t)(k0 + kk) * 1024 + n0 + a];
  }
  __syncthreads();
#pragma unroll
  for (int i = 0; i < 16; ++i) {
    int nn = i * 4 + q;
    w2t[(size_t)(n0 + nn) * 1024 + k0 + a] = f2bf(tile[a][nn]);
  }
}

// Wkt[b][d][m] = bf16( W1[256+m][d] - W1[512+m][d] + q[b][m]*W1[768+m][d] )
// + fused bias: biasb[b][d] = b1[d] + sum_m q[b][m]*(W1[m][d] + W1[512+m][d])
__global__ __launch_bounds__(256) void k_prep_wkt(const float* __restrict__ w1,
                                                  const float* __restrict__ query,
                                                  const float* __restrict__ b1,
                                                  short* __restrict__ wkt,
                                                  float* __restrict__ biasb) {
  __shared__ short tile[64][257];
  __shared__ float redm[64][4];
  const int b = blockIdx.x, d0 = blockIdx.y * 64;
  const int d = threadIdx.x & 63, mq = threadIdx.x >> 6;
  float bacc = 0.f;
#pragma unroll 4
  for (int i = 0; i < 64; ++i) {
    int m = i * 4 + mq;
    float qv = query[b * 256 + m];
    float wa = w1[(size_t)m * 1024 + d0 + d];
    float wb = w1[(size_t)(256 + m) * 1024 + d0 + d];
    float wc = w1[(size_t)(512 + m) * 1024 + d0 + d];
    float wd = w1[(size_t)(768 + m) * 1024 + d0 + d];
    tile[d][m] = f2bf(wb - wc + qv * wd);
    bacc += qv * (wa + wc);
  }
  redm[d][mq] = bacc;
  __syncthreads();
  const int m = threadIdx.x;
  for (int dd = 0; dd < 64; ++dd)
    wkt[((size_t)b * 1024 + d0 + dd) * 256 + m] = tile[dd][m];
  if (threadIdx.x < 64) {
    int dd = threadIdx.x;
    biasb[b * 1024 + d0 + dd] =
        redm[dd][0] + redm[dd][1] + redm[dd][2] + redm[dd][3] + b1[d0 + dd];
  }
}

// ---------------- 8-phase 256x256 GEMM (TN: C[i][j] = sum_k A[i][k]*B[j][k]) ----
// MODE 1: per-batch keys@Wk + bias, relu -> h1 (bf16).  M=N=1024/batch, K=256.
// MODE 2: h1@W2t + b2, relu, dot w_score -> score partials. M=65536, N=1024, K=1024.
// 512 thr (8 waves 2Mx4N), BM=BN=256, BK=64, LDS 128 KiB double-buffered,
// st-swizzle slot^=(row&7) on 16B chunks, counted vmcnt(4) at phi3/phi7 only.
// Swapped-operand MFMA (C^T fragments) -> packed 8B epilogue stores.

template <int MODE>
__global__ __launch_bounds__(512) void k_gemm8(const short* __restrict__ A,
                                               const short* __restrict__ B,
                                               const float* __restrict__ bias,
                                               const float* __restrict__ wscore,
                                               short* __restrict__ hout,
                                               float* __restrict__ spart) {
  __shared__ short lds[65536];  // 128 KiB (short units): buf{0,1} x {A h0,A h1,B h0,B h1} x 8192
  constexpr int SK = (MODE == 1) ? 256 : 1024;
  constexpr int KT = (MODE == 1) ? 4 : 16;

  const int tid = threadIdx.x;
  const int bx = blockIdx.x;
  const int L = (bx & 7) * 128 + (bx >> 3);  // XCD-bijective swizzle (1024%8==0)

  const short *Ab, *Bb;
  const float *biasp, *wsp = nullptr;
  short* houtp = nullptr;
  int rt, ct;
  if constexpr (MODE == 1) {
    const int b = L >> 4;
    rt = (L >> 2) & 3; ct = L & 3;
    Ab = A + ((size_t)b * 1024 + rt * 256) * 256;
    Bb = B + ((size_t)b * 1024 + ct * 256) * 256;
    biasp = bias + b * 1024 + ct * 256;
    houtp = hout + ((size_t)(b * 1024 + rt * 256)) * 1024 + ct * 256;
  } else {
    rt = L >> 2; ct = L & 3;
    Ab = A + (size_t)rt * 256 * 1024;
    Bb = B + (size_t)ct * 256 * 1024;
    biasp = bias + ct * 256;
    wsp = wscore + ct * 256;
  }

  // staging constants: chunk c -> row=c>>3, stored slot=c&7, src k16 = slot^(row&7)
  const int c0 = tid, c1 = 512 + tid;
  const int r0 = c0 >> 3, k0 = ((c0 & 7) ^ (r0 & 7)) * 8;
  const int r1 = c1 >> 3, k1 = ((c1 & 7) ^ (r1 & 7)) * 8;

  auto STAGE = [&](const short* gb, int kt, int half, int ldsb) {
    gload16(gb + (size_t)(half * 128 + r0) * SK + kt * 64 + k0, &lds[ldsb + c0 * 8]);
    gload16(gb + (size_t)(half * 128 + r1) * SK + kt * 64 + k1, &lds[ldsb + c1 * 8]);
  };

  // fragment-read constants
  const int lane = tid & 63, l15 = lane & 15, l4 = lane >> 4;
  const int wid = tid >> 6, wr = wid >> 2, wc = wid & 3;
  const int aoff0 = wr * 8192 + l15 * 64 + ((l4 ^ (l15 & 7)) * 8);
  const int aoff1 = wr * 8192 + l15 * 64 + (((4 + l4) ^ (l15 & 7)) * 8);
  const int boff0 = 16384 + (wc >> 1) * 8192 + (wc & 1) * 4096 + l15 * 64 +
                    ((l4 ^ (l15 & 7)) * 8);
  const int boff1 = 16384 + (wc >> 1) * 8192 + (wc & 1) * 4096 + l15 * 64 +
                    (((4 + l4) ^ (l15 & 7)) * 8);

  f32x4 acc[8][4];
#pragma unroll
  for (int m = 0; m < 8; ++m)
#pragma unroll
    for (int n = 0; n < 4; ++n) acc[m][n] = f32x4{0.f, 0.f, 0.f, 0.f};
  short8 af[4][2];
  short8 bf[2][2][2];

  // prologue: tile0 full + A(tile1); drain tile0, keep A(1) in flight
  STAGE(Ab, 0, 0, 0);
  STAGE(Ab, 0, 1, 8192);
  STAGE(Bb, 0, 0, 16384);
  STAGE(Bb, 0, 1, 24576);
  STAGE(Ab, 1, 0, 32768);
  STAGE(Ab, 1, 1, 40960);
  VMW(4);
  BAR();

  auto body = [&](int t, auto tag) {
    constexpr bool FULL = decltype(tag)::value;
    const int p = (t & 1) << 15;
    const int q = p ^ 32768;
    // phi0: tile t Q00; issue b1 early, counted wait (b1 lands under MFMA)
    RD_A(p, 0); RD_B(p, 0); RD_B(p, 1);
    STAGE(Bb, t + 1, 0, q + 16384);
    BAR(); LGKMW(4); MFMA_Q(0, 0); BAR();
    // phi1: Q01 (b1 already resident)
    STAGE(Bb, t + 1, 1, q + 24576);
    BAR(); LGKMW(0); MFMA_Q(0, 1); BAR();
    // phi2: Q11 (af<-a1)
    RD_A(p, 1);
    if constexpr (FULL) STAGE(Bb, t + 2, 0, p + 16384);
    BAR(); LGKMW(0); MFMA_Q(1, 1); BAR();
    // phi3: Q10
    if constexpr (FULL) STAGE(Bb, t + 2, 1, p + 24576);
    BAR();
    MFMA_Q(1, 0);
    if constexpr (FULL) { VMW(4); } else { VMW(0); }
    BAR();
    // phi4: tile t+1 (buf q) Q00
    RD_A(q, 0); RD_B(q, 0); RD_B(q, 1);
    if constexpr (FULL) STAGE(Ab, t + 2, 0, p + 0);
    BAR(); LGKMW(4); MFMA_Q(0, 0); BAR();
    // phi5: Q01
    if constexpr (FULL) STAGE(Ab, t + 2, 1, p + 8192);
    BAR(); LGKMW(0); MFMA_Q(0, 1); BAR();
    // phi6: Q11
    RD_A(q, 1);
    BAR(); LGKMW(0); MFMA_Q(1, 1); BAR();
    // phi7: Q10 + prefetch A(t+3) both halves
    if constexpr (FULL) { STAGE(Ab, t + 3, 0, q + 0); STAGE(Ab, t + 3, 1, q + 8192); }
    BAR();
    MFMA_Q(1, 0);
    if constexpr (FULL) { VMW(4); }
    BAR();
  };

#pragma nounroll
  for (int i = 0; i < KT / 2 - 1; ++i) body(2 * i, FullTag{});
  body(KT - 2, LastTag{});

  // ---------------- epilogue (C^T fragments: row=l15, col=l4*4+reg) ----------
  if constexpr (MODE == 1) {
    float bv[4][4];
#pragma unroll
    for (int n = 0; n < 4; ++n)
#pragma unroll
      for (int r2 = 0; r2 < 4; ++r2) bv[n][r2] = biasp[wc * 64 + n * 16 + l4 * 4 + r2];
#pragma unroll
    for (int m = 0; m < 8; ++m) {
      int row = wr * 128 + m * 16 + l15;
#pragma unroll
      for (int n = 0; n < 4; ++n) {
        s16x4 pk;
#pragma unroll
        for (int r2 = 0; r2 < 4; ++r2)
          pk[r2] = f2bf(fmaxf(acc[m][n][r2] + bv[n][r2], 0.f));
        *(s16x4*)&houtp[(size_t)row * 1024 + wc * 64 + n * 16 + l4 * 4] = pk;
      }
    }
  } else {
    float bv[4][4], wv[4][4];
#pragma unroll
    for (int n = 0; n < 4; ++n)
#pragma unroll
      for (int r2 = 0; r2 < 4; ++r2) {
        int c = wc * 64 + n * 16 + l4 * 4 + r2;
        bv[n][r2] = biasp[c];
        wv[n][r2] = wsp[c];
      }
    float* so = spart + ((size_t)(ct * 4 + wc) << 16) + rt * 256 + wr * 128;
#pragma unroll
    for (int m = 0; m < 8; ++m) {
      float s = 0.f;
#pragma unroll
      for (int n = 0; n < 4; ++n)
#pragma unroll
        for (int r2 = 0; r2 < 4; ++r2)
          s += fmaxf(acc[m][n][r2] + bv[n][r2], 0.f) * wv[n][r2];
      s += __shfl_xor(s, 16);
      s += __shfl_xor(s, 32);
      if (lane < 16) so[m * 16 + l15] = s;
    }
  }
}

// ---------------- softmax + output ----------------

__global__ __launch_bounds__(256) void k_softmax(const float* __restrict__ spart,
                                                 const float* __restrict__ mask,
                                                 const float* __restrict__ bscore,
                                                 float* __restrict__ attn) {
  const int b = blockIdx.x, tid = threadIdx.x;
  __shared__ float sm[1024];
  __shared__ float red[8];
  const float bs = bscore[0];
  float lmax = -3.0e38f;
  for (int t = tid; t < 1024; t += 256) {
    float s = bs;
#pragma unroll
    for (int c = 0; c < 16; ++c) s += spart[(size_t)c * 65536 + b * 1024 + t];
    float lg = s + mask[b * 1024 + t] * (-1e9f);
    sm[t] = lg;
    lmax = fmaxf(lmax, lg);
  }
  for (int o = 32; o; o >>= 1) lmax = fmaxf(lmax, __shfl_xor(lmax, o));
  const int wid = tid >> 6, lane = tid & 63;
  if (lane == 0) red[wid] = lmax;
  __syncthreads();
  float bmax = fmaxf(fmaxf(red[0], red[1]), fmaxf(red[2], red[3]));
  float lsum = 0.f;
  for (int t = tid; t < 1024; t += 256) {
    float e = __expf(sm[t] - bmax);
    sm[t] = e;
    lsum += e;
  }
  for (int o = 32; o; o >>= 1) lsum += __shfl_xor(lsum, o);
  __syncthreads();
  if (lane == 0) red[wid] = lsum;
  __syncthreads();
  float inv = 1.0f / (red[0] + red[1] + red[2] + red[3]);
  for (int t = tid; t < 1024; t += 256) attn[b * 1024 + t] = sm[t] * inv;
}

// out partials: block (b, ts): sum t in [ts*128, ts*128+128) over all 1024 d (float4/thread)
__global__ __launch_bounds__(256) void k_out(const float* __restrict__ attn,
                                             const float* __restrict__ values,
                                             float* __restrict__ part) {
  const int b = blockIdx.x >> 3, ts = blockIdx.x & 7;
  const int tid = threadIdx.x;
  __shared__ float at[128];
  if (tid < 128) at[tid] = attn[b * 1024 + ts * 128 + tid];
  __syncthreads();
  const float* vb = values + ((size_t)b * 1024 + ts * 128) * 1024 + tid * 4;
  f32x4 acc = {0.f, 0.f, 0.f, 0.f};
#pragma unroll 8
  for (int t = 0; t < 128; ++t) {
    f32x4v v = *(const f32x4v*)(vb + (size_t)t * 1024);
    float a = at[t];
    acc[0] += a * v[0]; acc[1] += a * v[1]; acc[2] += a * v[2]; acc[3] += a * v[3];
  }
  *(f32x4*)(part + ((size_t)(b * 8 + ts)) * 1024 + tid * 4) = acc;
}

__global__ __launch_bounds__(256) void k_red(const float* __restrict__ part,
                                             float* __restrict__ out) {
  const int b = blockIdx.x;
  const int c4 = threadIdx.x * 4;
  f32x4 s = {0.f, 0.f, 0.f, 0.f};
#pragma unroll
  for (int ts = 0; ts < 8; ++ts) {
    f32x4v v = *(const f32x4v*)(part + ((size_t)(b * 8 + ts)) * 1024 + c4);
    s[0] += v[0]; s[1] += v[1]; s[2] += v[2]; s[3] += v[3];
  }
  *(f32x4*)(out + b * 1024 + c4) = s;
}

// ---------------- launch ----------------

extern "C" void kernel_launch(void* const* d_in, const int* in_sizes, int n_in,
                              void* d_out, int out_size, void* d_ws, size_t ws_size,
                              hipStream_t stream) {
  const float* query  = (const float*)d_in[0];
  const float* keys   = (const float*)d_in[1];
  const float* values = (const float*)d_in[2];
  const float* mask   = (const float*)d_in[3];
  const float* W1     = (const float*)d_in[4];
  const float* b1     = (const float*)d_in[5];
  const float* W2     = (const float*)d_in[6];
  const float* b2     = (const float*)d_in[7];
  const float* wscore = (const float*)d_in[8];
  const float* bscore = (const float*)d_in[9];
  float* out = (float*)d_out;

  char* ws = (char*)d_ws;
  short* keysb = (short*)(ws);                   // 33,554,432 B
  short* wkt   = (short*)(ws + 33554432ull);     // 33,554,432 B
  short* w2t   = (short*)(ws + 67108864ull);     //  2,097,152 B
  float* biasb = (float*)(ws + 69206016ull);     //    262,144 B
  short* h1    = (short*)(ws + 69468160ull);     // 134,217,728 B
  float* spart = (float*)(ws + 203685888ull);    //  4,194,304 B
  float* attn  = (float*)(ws + 207880192ull);    //    262,144 B
  float* part  = (float*)(ws + 208142336ull);    //  2,097,152 B (total ~210 MB)

  k_prep_keys<<<8192, 256, 0, stream>>>(keys, keysb);
  k_prep_w2t<<<dim3(16, 16), 256, 0, stream>>>(W2, w2t);
  k_prep_wkt<<<dim3(64, 16), 256, 0, stream>>>(W1, query, b1, wkt, biasb);

  k_gemm8<1><<<1024, 512, 0, stream>>>(keysb, wkt, biasb, nullptr, h1, nullptr);
  k_gemm8<2><<<1024, 512, 0, stream>>>(h1, w2t, b2, wscore, nullptr, spart);

  k_softmax<<<64, 256, 0, stream>>>(spart, mask, bscore, attn);
  k_out<<<512, 256, 0, stream>>>(attn, values, part);
  k_red<<<64, 256, 0, stream>>>(part, out);
}